// Round 11
// baseline (180.463 us; speedup 1.0000x reference)
//
#include <hip/hip_runtime.h>
#include <hip/hip_bf16.h>

typedef __attribute__((ext_vector_type(8))) short short8;
typedef __attribute__((ext_vector_type(4))) float f32x4;

static const int BB = 2;
static const int LL = 512;
#define MIN_F32 (-3.4028234663852886e+38f)
// Masked gab sentinel: must stay FINITE in bf16 (bf16(-FLT_MAX) -> -inf -> nan diff)
#define NEG_BIG (-1.0e38f)
#define SCALING_F 0.08838834764831845f
#define SQ2PI 2.5066282746310002f

// raw v_exp_f32: 2^x
__device__ __forceinline__ float exp2_hw(float x) {
    float r; asm("v_exp_f32 %0, %1" : "=v"(r) : "v"(x)); return r;
}
// Fast exact-gelu: 0.5x(1+erf(x/sqrt2)) with A&S 7.1.26 erf (|err|<1.5e-7)
__device__ __forceinline__ float gelu_fast(float x) {
    float s  = x * 0.70710678118654752440f;
    float za = fabsf(s);
    float t  = __builtin_amdgcn_rcpf(fmaf(za, 0.3275911f, 1.0f));
    float p  = t * fmaf(t, fmaf(t, fmaf(t, fmaf(t, 1.061405429f, -1.453152027f),
                                        1.421413741f), -0.284496736f), 0.254829592f);
    float e  = __expf(-za * za);
    float q  = fmaf(-p, e, 1.0f);
    union { float f; unsigned u; } uq, us;
    uq.f = q; us.f = s;
    uq.u = (uq.u & 0x7FFFFFFFu) | (us.u & 0x80000000u);
    float hx = 0.5f * x;
    return fmaf(hx, uq.f, hx);
}
// packed bf16x2 via v_cvt_pk_bf16_f32 (RNE); lo -> low 16 bits
__device__ __forceinline__ unsigned pack_bf16x2(float lo, float hi) {
    __hip_bfloat162 h2 = __float22bfloat162_rn(float2{lo, hi});
    union { __hip_bfloat162 h; unsigned u; } v; v.h = h2;
    return v.u;
}
// f2bf scalar (weight staging only)
__device__ __forceinline__ unsigned short f2bf(float f) {
    union { float f; unsigned int u; } v; v.f = f;
    unsigned int u = v.u;
    return (unsigned short)((u + 0x7FFFu + ((u >> 16) & 1u)) >> 16);
}
// Row-swizzled LDS byte offset for [row][128 bf16] tiles (row stride 256B).
__device__ __forceinline__ int swz(int row, int bytecol) {
    return row * 256 + (bytecol ^ ((row & 7) << 4));
}

// ---------------- prep: transpose Wfe/Wp to [K][D] ----------------
__global__ __launch_bounds__(256) void prep_kernel(
    const float* __restrict__ wfe, const float* __restrict__ wp,
    float* __restrict__ wfet, float* __restrict__ wpt)
{
    int idx = blockIdx.x * 256 + threadIdx.x;
    int which = idx >> 17;
    int r = idx & 131071;
    int k = r >> 10;
    int d = r & 1023;
    if (which == 0) wfet[r] = wfe[d * 128 + k];
    else            wpt[r]  = wp[d * 128 + k];
}

// ---------------- main fused row kernel: one block per (b,i), 8 waves ----------------
// Wave-private tiles, barrier-free main loop. gab stores are buffered across
// round pairs so both 64B halves of every 128B line are issued back-to-back
// (R9/R10 lesson: halves separated by a compute round -> L2 partial-line RMW,
// FETCH 258MB. Full-line merge needs temporal adjacency, not just same-wave.)
__global__ __launch_bounds__(512, 4) void row_kernel(
    const float* __restrict__ pos,
    const int*   __restrict__ nte,
    const unsigned char* __restrict__ adj,
    const unsigned char* __restrict__ padm,
    const unsigned char* __restrict__ molm,
    const unsigned char* __restrict__ clnm,
    const float* __restrict__ gmean,
    const float* __restrict__ gstd,
    const float* __restrict__ gmul,
    const float* __restrict__ gbias,
    const float* __restrict__ w1,
    const float* __restrict__ b1,
    const float* __restrict__ w2,
    const float* __restrict__ b2,
    const float* __restrict__ pw,
    float* __restrict__ out_gab,
    float* __restrict__ pfe1,
    float* __restrict__ efsum)
{
    __shared__ __align__(16) char W1s[128 * 256];   // bf16 [jo][k], swizzled (32KB)
    __shared__ __align__(16) char wbuf[8][4096];    // per-wave ef->h buffer [16][128]bf16
    __shared__ float dist_row[512];
    __shared__ float xval[512];
    __shared__ unsigned char flgall[512];
    __shared__ float b1s[128];
    __shared__ float b2s[32];
    __shared__ float sred[16];

    const int t = threadIdx.x;
    const int row = blockIdx.x;     // b*512 + i
    const int b = row >> 9;
    const int i = row & 511;

    const int w  = t >> 6;          // wave 0..7
    const int l  = t & 63;          // lane
    const int lr = l & 15;
    const int lq = l >> 4;

    // ---- stage W1 as bf16, swizzled (one-time) ----
    for (int idx = t; idx < 2048; idx += 512) {
        int r16 = idx >> 4, c16 = idx & 15;
        const float* src = w1 + r16 * 128 + c16 * 8;
        float4 f0 = *(const float4*)(src);
        float4 f1 = *(const float4*)(src + 4);
        uint4 pk;
        pk.x = (unsigned)f2bf(f0.x) | ((unsigned)f2bf(f0.y) << 16);
        pk.y = (unsigned)f2bf(f0.z) | ((unsigned)f2bf(f0.w) << 16);
        pk.z = (unsigned)f2bf(f1.x) | ((unsigned)f2bf(f1.y) << 16);
        pk.w = (unsigned)f2bf(f1.z) | ((unsigned)f2bf(f1.w) << 16);
        *(uint4*)(W1s + swz(r16, c16 * 16)) = pk;
    }
    if (t < 128) b1s[t] = b1[t];
    if (t < 32)  b2s[t] = b2[t];

    const bool pad_i = padm[row] != 0;
    const bool force_adj = (clnm[row] != 0) || (molm[row] == 0);
    const float pix = pos[row * 3 + 0], piy = pos[row * 3 + 1], piz = pos[row * 3 + 2];

    // ---- per-j scalars for ALL 512 j (1 j / thread) ----
    {
        int2 e2 = ((const int2*)nte)[row * 512 + t];
        float mul = gmul[e2.x] + gmul[e2.y];
        float bia = gbias[e2.x] + gbias[e2.y];
        float dx = pix - pos[(b * 512 + t) * 3 + 0];
        float dy = piy - pos[(b * 512 + t) * 3 + 1];
        float dz = piz - pos[(b * 512 + t) * 3 + 2];
        float dist = sqrtf(dx * dx + dy * dy + dz * dz + 1e-12f);
        xval[t] = mul * dist + bia;
        int padj = padm[b * 512 + t] ? 1 : 0;
        int adje = (force_adj || adj[row * 512 + t]) ? 2 : 0;
        flgall[t] = (unsigned char)(padj | adje);
    }

    // ---- W2 fragments: global -> registers (one-time; no LDS) ----
    short8 w2f0[4], w2f1[4];
    #pragma unroll
    for (int ks = 0; ks < 4; ++ks) {
        const float* s0 = w2 + (0 * 16 + lr) * 128 + ks * 32 + lq * 8;
        const float* s1 = w2 + (1 * 16 + lr) * 128 + ks * 32 + lq * 8;
        float4 a0 = *(const float4*)s0, a1 = *(const float4*)(s0 + 4);
        float4 c0 = *(const float4*)s1, c1 = *(const float4*)(s1 + 4);
        union { uint4 u; short8 s; } cv;
        cv.u = make_uint4(pack_bf16x2(a0.x, a0.y), pack_bf16x2(a0.z, a0.w),
                          pack_bf16x2(a1.x, a1.y), pack_bf16x2(a1.z, a1.w));
        w2f0[ks] = cv.s;
        cv.u = make_uint4(pack_bf16x2(c0.x, c0.y), pack_bf16x2(c0.z, c0.w),
                          pack_bf16x2(c1.x, c1.y), pack_bf16x2(c1.z, c1.w));
        w2f1[ks] = cv.s;
    }

    // ---- gaussian params: 8 consecutive k per lane, exp2-folded ----
    const int k0 = lr * 8;
    float mean_q[8], istd_q[8], lnc_q[8], efacc[8];
    #pragma unroll
    for (int q = 0; q < 8; ++q) {
        float gsv = fabsf(gstd[k0 + q]) + 1e-5f;
        mean_q[q] = gmean[k0 + q];
        istd_q[q] = 0.84932180f / gsv;              // sqrt(0.5*log2(e))/sigma
        lnc_q[q]  = -log2f(SQ2PI * gsv);
        efacc[q]  = 0.f;
    }

    __syncthreads();    // the ONLY barrier before the tail

    char* myb = wbuf[w];
    f32x4 sv20 = {0.f,0.f,0.f,0.f}, sv21 = sv20;    // even-round gab buffer
    for (int rnd = 0; rnd < 4; ++rnd) {
        const int jbase = w * 64 + rnd * 16;
        // ef-gen: lane covers 4 j (jloc = lq + 4*jj) x its 8 k -> b128 writes
        #pragma unroll
        for (int jj = 0; jj < 4; ++jj) {
            int jloc = lq + jj * 4;
            int j = jbase + jloc;
            float x  = xval[j];
            float mk = (flgall[j] & 1) ? 0.0f : 1.0f;
            unsigned pk[4];
            #pragma unroll
            for (int q = 0; q < 4; ++q) {
                float a0 = (x - mean_q[2*q+0]) * istd_q[2*q+0];
                float a1 = (x - mean_q[2*q+1]) * istd_q[2*q+1];
                float e0 = exp2_hw(fmaf(a0, -a0, lnc_q[2*q+0]));
                float e1 = exp2_hw(fmaf(a1, -a1, lnc_q[2*q+1]));
                efacc[2*q+0] = fmaf(e0, mk, efacc[2*q+0]);
                efacc[2*q+1] = fmaf(e1, mk, efacc[2*q+1]);
                pk[q] = pack_bf16x2(e0, e1);
            }
            *(uint4*)(myb + swz(jloc, 2 * k0)) = make_uint4(pk[0], pk[1], pk[2], pk[3]);
        }
        // GEMM1: pull own ef frags to regs (frees buffer for h), then W1 x ef
        short8 eff[4];
        #pragma unroll
        for (int ks = 0; ks < 4; ++ks)
            eff[ks] = *(const short8*)(myb + swz(lr, ks * 64 + lq * 16));
        #pragma unroll
        for (int half = 0; half < 2; ++half) {
            f32x4 acc0 = {0.f,0.f,0.f,0.f}, acc1 = acc0, acc2 = acc0, acc3 = acc0;
            const int cb = half * 4;
            #pragma unroll
            for (int ks = 0; ks < 4; ++ks) {
                int bcol = ks * 64 + lq * 16;
                short8 av0 = *(const short8*)(W1s + swz((cb+0)*16 + lr, bcol));
                short8 av1 = *(const short8*)(W1s + swz((cb+1)*16 + lr, bcol));
                short8 av2 = *(const short8*)(W1s + swz((cb+2)*16 + lr, bcol));
                short8 av3 = *(const short8*)(W1s + swz((cb+3)*16 + lr, bcol));
                acc0 = __builtin_amdgcn_mfma_f32_16x16x32_bf16(av0, eff[ks], acc0, 0, 0, 0);
                acc1 = __builtin_amdgcn_mfma_f32_16x16x32_bf16(av1, eff[ks], acc1, 0, 0, 0);
                acc2 = __builtin_amdgcn_mfma_f32_16x16x32_bf16(av2, eff[ks], acc2, 0, 0, 0);
                acc3 = __builtin_amdgcn_mfma_f32_16x16x32_bf16(av3, eff[ks], acc3, 0, 0, 0);
            }
            #pragma unroll
            for (int ci = 0; ci < 4; ++ci) {
                f32x4 acc = (ci == 0) ? acc0 : (ci == 1) ? acc1 : (ci == 2) ? acc2 : acc3;
                int jo0 = (cb + ci) * 16 + lq * 4;
                float4 bb = *(const float4*)&b1s[jo0];
                float g0 = gelu_fast(acc[0] + bb.x);
                float g1 = gelu_fast(acc[1] + bb.y);
                float g2 = gelu_fast(acc[2] + bb.z);
                float g3 = gelu_fast(acc[3] + bb.w);
                *(uint2*)(myb + swz(lr, 2 * jo0)) =
                    make_uint2(pack_bf16x2(g0, g1), pack_bf16x2(g2, g3));
            }
        }
        // GEMM2: C'[n][j] = W2 @ h^T, all in-wave
        f32x4 acc20 = {0.f,0.f,0.f,0.f}, acc21 = acc20;
        #pragma unroll
        for (int ks = 0; ks < 4; ++ks) {
            short8 hf = *(const short8*)(myb + swz(lr, ks * 64 + lq * 16));
            acc20 = __builtin_amdgcn_mfma_f32_16x16x32_bf16(w2f0[ks], hf, acc20, 0, 0, 0);
            acc21 = __builtin_amdgcn_mfma_f32_16x16x32_bf16(w2f1[ks], hf, acc21, 0, 0, 0);
        }
        // epilogue: bias + mask into registers, head-sum, deferred paired stores
        int jg = jbase + lr;
        int fl = flgall[jg];
        bool kill = (fl & 1) || !(fl & 2);
        float dpart = 0.f;
        f32x4 o20, o21;
        #pragma unroll
        for (int mt = 0; mt < 2; ++mt) {
            f32x4 acc = mt ? acc21 : acc20;
            float4 bb = *(const float4*)&b2s[mt * 16 + lq * 4];
            f32x4 ov;
            #pragma unroll
            for (int r = 0; r < 4; ++r) {
                float raw = acc[r] + ((const float*)&bb)[r];
                dpart += raw;
                ov[r] = pad_i ? 0.0f : (kill ? NEG_BIG : raw);
            }
            if (mt) o21 = ov; else o20 = ov;
        }
        dpart += __shfl_xor(dpart, 16);
        dpart += __shfl_xor(dpart, 32);
        if (l < 16) {
            bool masked = pad_i || kill;
            dist_row[jg] = masked ? MIN_F32 : dpart;
        }
        if ((rnd & 1) == 0) {
            sv20 = o20; sv21 = o21;     // hold: store with sibling half next round
        } else {
            int jlo = w * 64 + (rnd - 1) * 16 + lr;   // 128B-line-aligned pair start
            #pragma unroll
            for (int mt = 0; mt < 2; ++mt) {
                f32x4 op = mt ? sv21 : sv20;
                f32x4 oc = mt ? o21 : o20;
                #pragma unroll
                for (int r = 0; r < 4; ++r) {
                    size_t base = ((size_t)(b * 32 + mt * 16 + lq * 4 + r) * 512 + i) * 512 + jlo;
                    out_gab[base]      = op[r];   // 64B half-line
                    out_gab[base + 16] = oc[r];   // sibling half, same cycle window
                }
            }
        }
    }

    __syncthreads();    // all waves done: wbuf free, dist_row complete

    // ---- efsum flush via wbuf scratch ----
    float* rb = (float*)wbuf;
    *(float4*)&rb[t * 8 + 0] = make_float4(efacc[0], efacc[1], efacc[2], efacc[3]);
    *(float4*)&rb[t * 8 + 4] = make_float4(efacc[4], efacc[5], efacc[6], efacc[7]);
    __syncthreads();
    if (t < 128) {
        float s = 0.f;
        #pragma unroll
        for (int sidx = 0; sidx < 32; ++sidx) s += rb[sidx * 128 + t];
        efsum[(size_t)row * 128 + t] = s;
    }

    // ---- softmax over dist_row ----
    float sv = dist_row[t] * SCALING_F;
    float v = sv;
    #pragma unroll
    for (int m = 32; m > 0; m >>= 1) v = fmaxf(v, __shfl_xor(v, m));
    if ((t & 63) == 0) sred[t >> 6] = v;
    __syncthreads();
    float mx = sred[0];
    #pragma unroll
    for (int w8 = 1; w8 < 8; ++w8) mx = fmaxf(mx, sred[w8]);
    float e = expf(sv - mx);
    v = e;
    #pragma unroll
    for (int m = 32; m > 0; m >>= 1) v += __shfl_xor(v, m);
    if ((t & 63) == 0) sred[8 + (t >> 6)] = v;
    __syncthreads();
    float sm = 0.f;
    #pragma unroll
    for (int w8 = 0; w8 < 8; ++w8) sm += sred[8 + w8];
    float p = e / sm;

    // ---- pfe1 via linearity: pfe1[k] = pw[k] . (sum_j p[j]*pos[j]) ----
    float px = pos[(b * 512 + t) * 3 + 0];
    float py = pos[(b * 512 + t) * 3 + 1];
    float pz = pos[(b * 512 + t) * 3 + 2];
    float vx = p * px, vy = p * py, vz = p * pz;
    #pragma unroll
    for (int m = 32; m > 0; m >>= 1) {
        vx += __shfl_xor(vx, m); vy += __shfl_xor(vy, m); vz += __shfl_xor(vz, m);
    }
    __syncthreads();      // rb re-use after efsum reads done
    if ((t & 63) == 0) {
        int w8 = t >> 6;
        rb[w8] = vx; rb[8 + w8] = vy; rb[16 + w8] = vz;
    }
    __syncthreads();
    if (t < 128) {
        float w0 = 0.f, w1v = 0.f, w2v = 0.f;
        #pragma unroll
        for (int w8 = 0; w8 < 8; ++w8) {
            w0 += rb[w8]; w1v += rb[8 + w8]; w2v += rb[16 + w8];
        }
        pfe1[(size_t)row * 128 + t] = pw[t * 3 + 0] * w0 + pw[t * 3 + 1] * w1v + pw[t * 3 + 2] * w2v;
    }
}

// ---------------- final projection: tiled f32 GEMM ----------------
__global__ __launch_bounds__(256) void pfe_kernel(
    const float* __restrict__ pfe1,
    const float* __restrict__ efsum,
    const float* __restrict__ wfet,   // [K=128][D=1024]
    const float* __restrict__ wpt,    // [K=128][D=1024]
    const float* __restrict__ pb,
    const unsigned char* __restrict__ padm,
    float* __restrict__ out)
{
    __shared__ __align__(16) float As[2 * 32 * 132];
    __shared__ __align__(16) float Bs[2 * 16 * 128];
    const int t  = threadIdx.x;
    const int tx = t & 31;
    const int ty = t >> 5;
    const int r0 = (blockIdx.x >> 3) * 32;
    const int d0 = (blockIdx.x & 7) * 128;

    #pragma unroll
    for (int q = 0; q < 16; ++q) {
        int ii = t + q * 256;
        int r = ii >> 7, k = ii & 127;
        As[(0 * 32 + r) * 132 + k] = pfe1 [(size_t)(r0 + r) * 128 + k];
        As[(1 * 32 + r) * 132 + k] = efsum[(size_t)(r0 + r) * 128 + k];
    }

    f32x4 acc[4];
    #pragma unroll
    for (int rr = 0; rr < 4; ++rr) acc[rr] = (f32x4){0.f, 0.f, 0.f, 0.f};

    for (int kc = 0; kc < 8; ++kc) {
        __syncthreads();
        #pragma unroll
        for (int q = 0; q < 2; ++q) {
            int ii = t + q * 256;
            int kr = ii >> 5, dq = ii & 31;
            f32x4 v0 = ((const f32x4*)(wfet + (size_t)(kc * 16 + kr) * 1024 + d0))[dq];
            f32x4 v1 = ((const f32x4*)(wpt  + (size_t)(kc * 16 + kr) * 1024 + d0))[dq];
            *(f32x4*)&Bs[(0 * 16 + kr) * 128 + dq * 4] = v0;
            *(f32x4*)&Bs[(1 * 16 + kr) * 128 + dq * 4] = v1;
        }
        __syncthreads();
        #pragma unroll
        for (int k4 = 0; k4 < 4; ++k4) {
            int kb = kc * 16 + k4 * 4;
            f32x4 a0[4], a1[4];
            #pragma unroll
            for (int rr = 0; rr < 4; ++rr) {
                int r = ty * 4 + rr;
                a0[rr] = *(const f32x4*)&As[(0 * 32 + r) * 132 + kb];
                a1[rr] = *(const f32x4*)&As[(1 * 32 + r) * 132 + kb];
            }
            #pragma unroll
            for (int kq = 0; kq < 4; ++kq) {
                f32x4 b0 = *(const f32x4*)&Bs[(0 * 16 + k4 * 4 + kq) * 128 + tx * 4];
                f32x4 b1 = *(const f32x4*)&Bs[(1 * 16 + k4 * 4 + kq) * 128 + tx * 4];
                #pragma unroll
                for (int rr = 0; rr < 4; ++rr) {
                    acc[rr] += a0[rr][kq] * b0 + a1[rr][kq] * b1;
                }
            }
        }
    }

    f32x4 bv = *(const f32x4*)&pb[d0 + tx * 4];
    #pragma unroll
    for (int rr = 0; rr < 4; ++rr) {
        int row = r0 + ty * 4 + rr;
        f32x4 o = acc[rr] + bv;
        if (padm[row]) o = (f32x4){0.f, 0.f, 0.f, 0.f};
        *(f32x4*)&out[(size_t)row * 1024 + d0 + tx * 4] = o;
    }
}

extern "C" void kernel_launch(void* const* d_in, const int* in_sizes, int n_in,
                              void* d_out, int out_size, void* d_ws, size_t ws_size,
                              hipStream_t stream) {
    const float* pos  = (const float*)d_in[0];
    const int*   nte  = (const int*)d_in[1];
    const unsigned char* adj  = (const unsigned char*)d_in[2];
    const unsigned char* padm = (const unsigned char*)d_in[3];
    const unsigned char* molm = (const unsigned char*)d_in[4];
    const unsigned char* clnm = (const unsigned char*)d_in[5];
    const float* pw    = (const float*)d_in[6];
    const float* wfe   = (const float*)d_in[7];
    const float* gmean = (const float*)d_in[8];
    const float* gstd  = (const float*)d_in[9];
    const float* gmul  = (const float*)d_in[10];
    const float* gbias = (const float*)d_in[11];
    const float* w1    = (const float*)d_in[12];
    const float* b1    = (const float*)d_in[13];
    const float* w2    = (const float*)d_in[14];
    const float* b2    = (const float*)d_in[15];
    const float* wp    = (const float*)d_in[16];
    const float* pb    = (const float*)d_in[17];

    float* out      = (float*)d_out;
    float* out_pfe  = out;
    float* out_gab  = out + (size_t)BB * LL * 1024;

    float* ws    = (float*)d_ws;
    float* pfe1  = ws;                  // 131072
    float* efsum = ws + 131072;         // 131072
    float* wfet  = ws + 262144;         // 131072
    float* wpt   = ws + 393216;         // 131072

    prep_kernel<<<1024, 256, 0, stream>>>(wfe, wp, wfet, wpt);
    row_kernel<<<BB * LL, 512, 0, stream>>>(pos, nte, adj, padm, molm, clnm,
                                            gmean, gstd, gmul, gbias,
                                            w1, b1, w2, b2, pw,
                                            out_gab, pfe1, efsum);
    pfe_kernel<<<256, 256, 0, stream>>>(pfe1, efsum, wfet, wpt, pb, padm, out_pfe);
}

// Round 12
// 109.749 us; speedup vs baseline: 1.6443x; 1.6443x over previous
//
#include <hip/hip_runtime.h>
#include <hip/hip_bf16.h>

typedef __attribute__((ext_vector_type(8))) short short8;
typedef __attribute__((ext_vector_type(4))) float f32x4;

static const int BB = 2;
static const int LL = 512;
#define MIN_F32 (-3.4028234663852886e+38f)
// Masked gab sentinel: must stay FINITE in bf16 (bf16(-FLT_MAX) -> -inf -> nan diff)
#define NEG_BIG (-1.0e38f)
#define SCALING_F 0.08838834764831845f
#define SQ2PI 2.5066282746310002f

// Fast exact-gelu: 0.5x(1+erf(x/sqrt2)) with A&S 7.1.26 erf (|err|<1.5e-7)
__device__ __forceinline__ float gelu_fast(float x) {
    float s  = x * 0.70710678118654752440f;
    float za = fabsf(s);
    float t  = __builtin_amdgcn_rcpf(fmaf(za, 0.3275911f, 1.0f));
    float p  = t * fmaf(t, fmaf(t, fmaf(t, fmaf(t, 1.061405429f, -1.453152027f),
                                        1.421413741f), -0.284496736f), 0.254829592f);
    float e  = __expf(-za * za);
    float q  = fmaf(-p, e, 1.0f);
    union { float f; unsigned u; } uq, us;
    uq.f = q; us.f = s;
    uq.u = (uq.u & 0x7FFFFFFFu) | (us.u & 0x80000000u);
    float hx = 0.5f * x;
    return fmaf(hx, uq.f, hx);
}
// packed bf16x2 via v_cvt_pk_bf16_f32 (RNE); lo -> low 16 bits
__device__ __forceinline__ unsigned pack_bf16x2(float lo, float hi) {
    __hip_bfloat162 h2 = __float22bfloat162_rn(float2{lo, hi});
    union { __hip_bfloat162 h; unsigned u; } v; v.h = h2;
    return v.u;
}
// f2bf scalar (weight staging only, once per block)
__device__ __forceinline__ unsigned short f2bf(float f) {
    union { float f; unsigned int u; } v; v.f = f;
    unsigned int u = v.u;
    return (unsigned short)((u + 0x7FFFu + ((u >> 16) & 1u)) >> 16);
}
// Row-swizzled LDS byte offset for [row][128 bf16] tiles (row stride 256B).
__device__ __forceinline__ int swz(int row, int bytecol) {
    return row * 256 + (bytecol ^ ((row & 7) << 4));
}

// ---------------- main fused row kernel: one block per (b,i), 8 waves ----------------
// R8 lockstep structure (best measured: 94.4us, FETCH 4.8MB). Blocks >= 1024 do the
// wfe/wp transpose (former prep_kernel) so that launch disappears from the timeline.
// R9-R11 lesson: wave-private barrier-free variants amplified gab HBM traffic 4-5x
// (drifted 64B store bursts); lockstep per-tile store slabs keep L2 write merge clean.
__global__ __launch_bounds__(512, 4) void row_kernel(
    const float* __restrict__ pos,
    const int*   __restrict__ nte,
    const unsigned char* __restrict__ adj,
    const unsigned char* __restrict__ padm,
    const unsigned char* __restrict__ molm,
    const unsigned char* __restrict__ clnm,
    const float* __restrict__ gmean,
    const float* __restrict__ gstd,
    const float* __restrict__ gmul,
    const float* __restrict__ gbias,
    const float* __restrict__ w1,
    const float* __restrict__ b1,
    const float* __restrict__ w2,
    const float* __restrict__ b2,
    const float* __restrict__ pw,
    const float* __restrict__ wfe,
    const float* __restrict__ wp,
    float* __restrict__ out_gab,
    float* __restrict__ pfe1,
    float* __restrict__ efsum,
    float* __restrict__ wfet,
    float* __restrict__ wpt)
{
    const int t = threadIdx.x;

    // ---- tail blocks: weight transpose for pfe_kernel (former prep_kernel) ----
    if (blockIdx.x >= 1024) {
        int bid = blockIdx.x - 1024;          // 0..127
        #pragma unroll
        for (int q = 0; q < 4; ++q) {
            int idx = bid * 2048 + q * 512 + t;   // 0..262143
            int which = idx >> 17;
            int r = idx & 131071;                  // k*1024 + d
            int k = r >> 10;
            int d = r & 1023;
            if (which == 0) wfet[r] = wfe[d * 128 + k];
            else            wpt[r]  = wp[d * 128 + k];
        }
        return;
    }

    __shared__ __align__(16) char W1s[128 * 256];  // bf16 [jo=128][k=128], swizzled
    __shared__ __align__(16) char W2s[32 * 256];   // bf16 [n=32][jo=128], swizzled
    __shared__ __align__(16) char efs[64 * 256];   // bf16 [j=64][k=128], swizzled; scratch at end
    __shared__ __align__(16) char hs [64 * 256];   // bf16 [j=64][jo=128], swizzled
    __shared__ float dist_row[512];
    __shared__ float xval[512];
    __shared__ unsigned char flgall[512];
    __shared__ float b1s[128];
    __shared__ float b2s[32];
    __shared__ float sred[16];
    __shared__ float dsump[128];

    const int row = blockIdx.x;     // b*512 + i
    const int b = row >> 9;
    const int i = row & 511;

    const int w  = t >> 6;          // wave 0..7
    const int l  = t & 63;          // lane
    const int lr = l & 15;          // frag row/col index
    const int lq = l >> 4;          // frag k-group

    // ---- stage W1 + W2 as bf16, swizzled ----
    for (int idx = t; idx < 2048 + 512; idx += 512) {
        const float* src; char* dst; int r16, c16;
        if (idx < 2048) { r16 = idx >> 4;          c16 = idx & 15; src = w1 + r16 * 128 + c16 * 8; dst = W1s; }
        else            { r16 = (idx - 2048) >> 4; c16 = (idx - 2048) & 15; src = w2 + r16 * 128 + c16 * 8; dst = W2s; }
        float4 f0 = *(const float4*)(src);
        float4 f1 = *(const float4*)(src + 4);
        uint4 pk;
        pk.x = (unsigned)f2bf(f0.x) | ((unsigned)f2bf(f0.y) << 16);
        pk.y = (unsigned)f2bf(f0.z) | ((unsigned)f2bf(f0.w) << 16);
        pk.z = (unsigned)f2bf(f1.x) | ((unsigned)f2bf(f1.y) << 16);
        pk.w = (unsigned)f2bf(f1.z) | ((unsigned)f2bf(f1.w) << 16);
        *(uint4*)(dst + swz(r16, c16 * 16)) = pk;
    }
    if (t < 128) b1s[t] = b1[t];
    if (t < 32)  b2s[t] = b2[t];

    const bool pad_i = padm[row] != 0;
    const bool force_adj = (clnm[row] != 0) || (molm[row] == 0);
    const float pix = pos[row * 3 + 0], piy = pos[row * 3 + 1], piz = pos[row * 3 + 2];

    // ---- per-j scalars for ALL 512 j, fully parallel (1 j / thread) ----
    {
        int2 e2 = ((const int2*)nte)[row * 512 + t];
        float mul = gmul[e2.x] + gmul[e2.y];
        float bia = gbias[e2.x] + gbias[e2.y];
        float dx = pix - pos[(b * 512 + t) * 3 + 0];
        float dy = piy - pos[(b * 512 + t) * 3 + 1];
        float dz = piz - pos[(b * 512 + t) * 3 + 2];
        float dist = sqrtf(dx * dx + dy * dy + dz * dz + 1e-12f);
        xval[t] = mul * dist + bia;
        int padj = padm[b * 512 + t] ? 1 : 0;
        int adje = (force_adj || adj[row * 512 + t]) ? 2 : 0;
        flgall[t] = (unsigned char)(padj | adje);
    }

    // ---- per-thread gaussian params: 8 consecutive k per thread ----
    const int k0 = (t & 15) * 8;
    const int js = t >> 4;          // j-slot 0..31
    float mean_q[8], istd_q[8], lnc_q[8], efacc[8];
    #pragma unroll
    for (int q = 0; q < 8; ++q) {
        float gsv = fabsf(gstd[k0 + q]) + 1e-5f;
        mean_q[q] = gmean[k0 + q];
        istd_q[q] = 1.0f / gsv;
        lnc_q[q]  = -logf(SQ2PI * gsv);
        efacc[q]  = 0.f;
    }

    __syncthreads();

    for (int tile = 0; tile < 8; ++tile) {
        const int j0 = tile * 64;
        // P1: ef-gen, k-major packed (+ previous tile's dist combine rides here)
        if (tile > 0 && t < 64) {
            int fl = flgall[j0 - 64 + t];
            bool masked = pad_i || (fl & 1) || !(fl & 2);
            dist_row[j0 - 64 + t] = masked ? MIN_F32 : (dsump[t] + dsump[64 + t]);
        }
        #pragma unroll
        for (int jj = 0; jj < 2; ++jj) {
            int j = js + jj * 32;
            float x  = xval[j0 + j];
            float mk = (flgall[j0 + j] & 1) ? 0.0f : 1.0f;
            unsigned pk[4];
            #pragma unroll
            for (int q = 0; q < 4; ++q) {
                float a0 = (x - mean_q[2*q+0]) * istd_q[2*q+0];
                float a1 = (x - mean_q[2*q+1]) * istd_q[2*q+1];
                float e0 = __expf(fmaf(a0 * a0, -0.5f, lnc_q[2*q+0]));
                float e1 = __expf(fmaf(a1 * a1, -0.5f, lnc_q[2*q+1]));
                efacc[2*q+0] = fmaf(e0, mk, efacc[2*q+0]);
                efacc[2*q+1] = fmaf(e1, mk, efacc[2*q+1]);
                pk[q] = pack_bf16x2(e0, e1);
            }
            *(uint4*)(efs + swz(j, 2 * k0)) = make_uint4(pk[0], pk[1], pk[2], pk[3]);
        }
        __syncthreads();
        // P2: GEMM1 swapped  D[jo][j] = W1 @ ef^T, gelu, packed b64 stores to hs[j][jo]
        {
            const int jobase = (w & 3) * 32;     // 2 jo-tiles
            const int jbase  = (w >> 2) * 32;    // 2 j-tiles
            f32x4 a00 = {0.f,0.f,0.f,0.f}, a01 = a00, a10 = a00, a11 = a00;
            #pragma unroll
            for (int ks = 0; ks < 4; ++ks) {
                int bcol = ks * 64 + lq * 16;
                short8 av0 = *(const short8*)(W1s + swz(jobase + lr, bcol));
                short8 av1 = *(const short8*)(W1s + swz(jobase + 16 + lr, bcol));
                short8 bv0 = *(const short8*)(efs + swz(jbase + lr, bcol));
                short8 bv1 = *(const short8*)(efs + swz(jbase + 16 + lr, bcol));
                a00 = __builtin_amdgcn_mfma_f32_16x16x32_bf16(av0, bv0, a00, 0, 0, 0);
                a01 = __builtin_amdgcn_mfma_f32_16x16x32_bf16(av0, bv1, a01, 0, 0, 0);
                a10 = __builtin_amdgcn_mfma_f32_16x16x32_bf16(av1, bv0, a10, 0, 0, 0);
                a11 = __builtin_amdgcn_mfma_f32_16x16x32_bf16(av1, bv1, a11, 0, 0, 0);
            }
            #pragma unroll
            for (int mi = 0; mi < 2; ++mi) {
                int jo0 = jobase + mi * 16 + lq * 4;
                float4 bb = *(const float4*)&b1s[jo0];
                #pragma unroll
                for (int ci = 0; ci < 2; ++ci) {
                    f32x4 acc = (mi == 0) ? (ci == 0 ? a00 : a01) : (ci == 0 ? a10 : a11);
                    int j = jbase + ci * 16 + lr;
                    float g0 = gelu_fast(acc[0] + bb.x);
                    float g1 = gelu_fast(acc[1] + bb.y);
                    float g2 = gelu_fast(acc[2] + bb.z);
                    float g3 = gelu_fast(acc[3] + bb.w);
                    uint2 pv = make_uint2(pack_bf16x2(g0, g1), pack_bf16x2(g2, g3));
                    *(uint2*)(hs + swz(j, 2 * jo0)) = pv;
                }
            }
        }
        __syncthreads();
        // P3: GEMM2 transposed  C'[n][j] = W2 @ h^T  (lockstep store slab)
        {
            const int mt = w >> 2;           // n-tile (0/1)
            const int jt2 = w & 3;           // j-tile
            f32x4 acc = (f32x4){0.f, 0.f, 0.f, 0.f};
            #pragma unroll
            for (int ks = 0; ks < 4; ++ks) {
                int bcol = ks * 64 + lq * 16;
                short8 av = *(const short8*)(W2s + swz(mt * 16 + lr, bcol));
                short8 bv = *(const short8*)(hs + swz(jt2 * 16 + lr, bcol));
                acc = __builtin_amdgcn_mfma_f32_16x16x32_bf16(av, bv, acc, 0, 0, 0);
            }
            int jl = jt2 * 16 + lr;
            int jg = j0 + jl;
            int fl = flgall[jg];
            bool kill = (fl & 1) || !(fl & 2);
            float dpart = 0.f;
            size_t base = ((size_t)(b * 32 + mt * 16 + lq * 4) * 512 + i) * 512 + jg;
            #pragma unroll
            for (int r = 0; r < 4; ++r) {
                float raw = acc[r] + b2s[mt * 16 + lq * 4 + r];
                dpart += raw;
                float outv = pad_i ? 0.0f : (kill ? NEG_BIG : raw);
                out_gab[base + (size_t)r * 262144] = outv;
            }
            dpart += __shfl_xor(dpart, 16);
            dpart += __shfl_xor(dpart, 32);
            if (l < 16) dsump[mt * 64 + jl] = dpart;
        }
        __syncthreads();
    }

    // last tile's dist combine + efsum flush (efs free -> scratch)
    float* rb = (float*)efs;
    if (t < 64) {
        int fl = flgall[448 + t];
        bool masked = pad_i || (fl & 1) || !(fl & 2);
        dist_row[448 + t] = masked ? MIN_F32 : (dsump[t] + dsump[64 + t]);
    }
    // rb[js*128 + k0 + q] = efacc[q]
    *(float4*)&rb[t * 8 + 0] = make_float4(efacc[0], efacc[1], efacc[2], efacc[3]);
    *(float4*)&rb[t * 8 + 4] = make_float4(efacc[4], efacc[5], efacc[6], efacc[7]);
    __syncthreads();
    if (t < 128) {
        float s = 0.f;
        #pragma unroll
        for (int sidx = 0; sidx < 32; ++sidx) s += rb[sidx * 128 + t];
        efsum[(size_t)row * 128 + t] = s;
    }

    // ---- softmax over dist_row ----
    float sv = dist_row[t] * SCALING_F;
    float v = sv;
    #pragma unroll
    for (int m = 32; m > 0; m >>= 1) v = fmaxf(v, __shfl_xor(v, m));
    if ((t & 63) == 0) sred[t >> 6] = v;
    __syncthreads();
    float mx = sred[0];
    #pragma unroll
    for (int w8 = 1; w8 < 8; ++w8) mx = fmaxf(mx, sred[w8]);
    float e = expf(sv - mx);
    v = e;
    #pragma unroll
    for (int m = 32; m > 0; m >>= 1) v += __shfl_xor(v, m);
    if ((t & 63) == 0) sred[8 + (t >> 6)] = v;
    __syncthreads();
    float sm = 0.f;
    #pragma unroll
    for (int w8 = 0; w8 < 8; ++w8) sm += sred[8 + w8];
    float p = e / sm;

    // ---- pfe1 via linearity: pfe1[k] = pw[k] . (sum_j p[j]*pos[j]) ----
    float px = pos[(b * 512 + t) * 3 + 0];
    float py = pos[(b * 512 + t) * 3 + 1];
    float pz = pos[(b * 512 + t) * 3 + 2];
    float vx = p * px, vy = p * py, vz = p * pz;
    #pragma unroll
    for (int m = 32; m > 0; m >>= 1) {
        vx += __shfl_xor(vx, m); vy += __shfl_xor(vy, m); vz += __shfl_xor(vz, m);
    }
    __syncthreads();      // rb re-use after efsum reads done
    if ((t & 63) == 0) {
        int w8 = t >> 6;
        rb[w8] = vx; rb[8 + w8] = vy; rb[16 + w8] = vz;
    }
    __syncthreads();
    if (t < 128) {
        float w0 = 0.f, w1v = 0.f, w2v = 0.f;
        #pragma unroll
        for (int w8 = 0; w8 < 8; ++w8) {
            w0 += rb[w8]; w1v += rb[8 + w8]; w2v += rb[16 + w8];
        }
        pfe1[(size_t)row * 128 + t] = pw[t * 3 + 0] * w0 + pw[t * 3 + 1] * w1v + pw[t * 3 + 2] * w2v;
    }
}

// ---------------- final projection: tiled f32 GEMM ----------------
__global__ __launch_bounds__(256) void pfe_kernel(
    const float* __restrict__ pfe1,
    const float* __restrict__ efsum,
    const float* __restrict__ wfet,   // [K=128][D=1024]
    const float* __restrict__ wpt,    // [K=128][D=1024]
    const float* __restrict__ pb,
    const unsigned char* __restrict__ padm,
    float* __restrict__ out)
{
    __shared__ __align__(16) float As[2 * 32 * 132];
    __shared__ __align__(16) float Bs[2 * 16 * 128];
    const int t  = threadIdx.x;
    const int tx = t & 31;
    const int ty = t >> 5;
    const int r0 = (blockIdx.x >> 3) * 32;
    const int d0 = (blockIdx.x & 7) * 128;

    #pragma unroll
    for (int q = 0; q < 16; ++q) {
        int ii = t + q * 256;
        int r = ii >> 7, k = ii & 127;
        As[(0 * 32 + r) * 132 + k] = pfe1 [(size_t)(r0 + r) * 128 + k];
        As[(1 * 32 + r) * 132 + k] = efsum[(size_t)(r0 + r) * 128 + k];
    }

    f32x4 acc[4];
    #pragma unroll
    for (int rr = 0; rr < 4; ++rr) acc[rr] = (f32x4){0.f, 0.f, 0.f, 0.f};

    for (int kc = 0; kc < 8; ++kc) {
        __syncthreads();
        #pragma unroll
        for (int q = 0; q < 2; ++q) {
            int ii = t + q * 256;
            int kr = ii >> 5, dq = ii & 31;
            f32x4 v0 = ((const f32x4*)(wfet + (size_t)(kc * 16 + kr) * 1024 + d0))[dq];
            f32x4 v1 = ((const f32x4*)(wpt  + (size_t)(kc * 16 + kr) * 1024 + d0))[dq];
            *(f32x4*)&Bs[(0 * 16 + kr) * 128 + dq * 4] = v0;
            *(f32x4*)&Bs[(1 * 16 + kr) * 128 + dq * 4] = v1;
        }
        __syncthreads();
        #pragma unroll
        for (int k4 = 0; k4 < 4; ++k4) {
            int kb = kc * 16 + k4 * 4;
            f32x4 a0[4], a1[4];
            #pragma unroll
            for (int rr = 0; rr < 4; ++rr) {
                int r = ty * 4 + rr;
                a0[rr] = *(const f32x4*)&As[(0 * 32 + r) * 132 + kb];
                a1[rr] = *(const f32x4*)&As[(1 * 32 + r) * 132 + kb];
            }
            #pragma unroll
            for (int kq = 0; kq < 4; ++kq) {
                f32x4 b0 = *(const f32x4*)&Bs[(0 * 16 + k4 * 4 + kq) * 128 + tx * 4];
                f32x4 b1 = *(const f32x4*)&Bs[(1 * 16 + k4 * 4 + kq) * 128 + tx * 4];
                #pragma unroll
                for (int rr = 0; rr < 4; ++rr) {
                    acc[rr] += a0[rr][kq] * b0 + a1[rr][kq] * b1;
                }
            }
        }
    }

    f32x4 bv = *(const f32x4*)&pb[d0 + tx * 4];
    #pragma unroll
    for (int rr = 0; rr < 4; ++rr) {
        int row = r0 + ty * 4 + rr;
        f32x4 o = acc[rr] + bv;
        if (padm[row]) o = (f32x4){0.f, 0.f, 0.f, 0.f};
        *(f32x4*)&out[(size_t)row * 1024 + d0 + tx * 4] = o;
    }
}

extern "C" void kernel_launch(void* const* d_in, const int* in_sizes, int n_in,
                              void* d_out, int out_size, void* d_ws, size_t ws_size,
                              hipStream_t stream) {
    const float* pos  = (const float*)d_in[0];
    const int*   nte  = (const int*)d_in[1];
    const unsigned char* adj  = (const unsigned char*)d_in[2];
    const unsigned char* padm = (const unsigned char*)d_in[3];
    const unsigned char* molm = (const unsigned char*)d_in[4];
    const unsigned char* clnm = (const unsigned char*)d_in[5];
    const float* pw    = (const float*)d_in[6];
    const float* wfe   = (const float*)d_in[7];
    const float* gmean = (const float*)d_in[8];
    const float* gstd  = (const float*)d_in[9];
    const float* gmul  = (const float*)d_in[10];
    const float* gbias = (const float*)d_in[11];
    const float* w1    = (const float*)d_in[12];
    const float* b1    = (const float*)d_in[13];
    const float* w2    = (const float*)d_in[14];
    const float* b2    = (const float*)d_in[15];
    const float* wp    = (const float*)d_in[16];
    const float* pb    = (const float*)d_in[17];

    float* out      = (float*)d_out;
    float* out_pfe  = out;
    float* out_gab  = out + (size_t)BB * LL * 1024;

    float* ws    = (float*)d_ws;
    float* pfe1  = ws;                  // 131072
    float* efsum = ws + 131072;         // 131072
    float* wfet  = ws + 262144;         // 131072
    float* wpt   = ws + 393216;         // 131072

    row_kernel<<<BB * LL + 128, 512, 0, stream>>>(pos, nte, adj, padm, molm, clnm,
                                                  gmean, gstd, gmul, gbias,
                                                  w1, b1, w2, b2, pw, wfe, wp,
                                                  out_gab, pfe1, efsum, wfet, wpt);
    pfe_kernel<<<256, 256, 0, stream>>>(pfe1, efsum, wfet, wpt, pb, padm, out_pfe);
}

// Round 13
// 109.557 us; speedup vs baseline: 1.6472x; 1.0018x over previous
//
#include <hip/hip_runtime.h>
#include <hip/hip_bf16.h>

typedef __attribute__((ext_vector_type(8))) short short8;
typedef __attribute__((ext_vector_type(4))) float f32x4;

static const int BB = 2;
static const int LL = 512;
#define MIN_F32 (-3.4028234663852886e+38f)
// Masked gab sentinel: must stay FINITE in bf16 (bf16(-FLT_MAX) -> -inf -> nan diff)
#define NEG_BIG (-1.0e38f)
#define SCALING_F 0.08838834764831845f
#define SQ2PI 2.5066282746310002f

// Fast exact-gelu: 0.5x(1+erf(x/sqrt2)) with A&S 7.1.26 erf (|err|<1.5e-7)
__device__ __forceinline__ float gelu_fast(float x) {
    float s  = x * 0.70710678118654752440f;
    float za = fabsf(s);
    float t  = __builtin_amdgcn_rcpf(fmaf(za, 0.3275911f, 1.0f));
    float p  = t * fmaf(t, fmaf(t, fmaf(t, fmaf(t, 1.061405429f, -1.453152027f),
                                        1.421413741f), -0.284496736f), 0.254829592f);
    float e  = __expf(-za * za);
    float q  = fmaf(-p, e, 1.0f);
    union { float f; unsigned u; } uq, us;
    uq.f = q; us.f = s;
    uq.u = (uq.u & 0x7FFFFFFFu) | (us.u & 0x80000000u);
    float hx = 0.5f * x;
    return fmaf(hx, uq.f, hx);
}
// packed bf16x2 via v_cvt_pk_bf16_f32 (RNE); lo -> low 16 bits
__device__ __forceinline__ unsigned pack_bf16x2(float lo, float hi) {
    __hip_bfloat162 h2 = __float22bfloat162_rn(float2{lo, hi});
    union { __hip_bfloat162 h; unsigned u; } v; v.h = h2;
    return v.u;
}
// f2bf scalar (weight staging only, once per block)
__device__ __forceinline__ unsigned short f2bf(float f) {
    union { float f; unsigned int u; } v; v.f = f;
    unsigned int u = v.u;
    return (unsigned short)((u + 0x7FFFu + ((u >> 16) & 1u)) >> 16);
}
// Row-swizzled LDS byte offset for [row][128 bf16] tiles (row stride 256B).
__device__ __forceinline__ int swz(int row, int bytecol) {
    return row * 256 + (bytecol ^ ((row & 7) << 4));
}

// ---------------- main fused row kernel: one block per (b,i), 8 waves ----------------
// R8 lockstep structure (best measured: 94.4us, FETCH 4.8MB). Blocks >= 1024 do the
// wfe/wp transpose (former prep_kernel) so that launch disappears from the timeline.
// R9-R11 lesson: wave-private barrier-free variants amplified gab HBM traffic 4-5x
// (drifted 64B store bursts); lockstep per-tile store slabs keep L2 write merge clean.
__global__ __launch_bounds__(512, 4) void row_kernel(
    const float* __restrict__ pos,
    const int*   __restrict__ nte,
    const unsigned char* __restrict__ adj,
    const unsigned char* __restrict__ padm,
    const unsigned char* __restrict__ molm,
    const unsigned char* __restrict__ clnm,
    const float* __restrict__ gmean,
    const float* __restrict__ gstd,
    const float* __restrict__ gmul,
    const float* __restrict__ gbias,
    const float* __restrict__ w1,
    const float* __restrict__ b1,
    const float* __restrict__ w2,
    const float* __restrict__ b2,
    const float* __restrict__ pw,
    const float* __restrict__ wfe,
    const float* __restrict__ wp,
    float* __restrict__ out_gab,
    float* __restrict__ pfe1,
    float* __restrict__ efsum,
    float* __restrict__ wfet,
    float* __restrict__ wpt)
{
    const int t = threadIdx.x;

    // ---- tail blocks: weight transpose for pfe_kernel (former prep_kernel) ----
    if (blockIdx.x >= 1024) {
        int bid = blockIdx.x - 1024;          // 0..127
        #pragma unroll
        for (int q = 0; q < 4; ++q) {
            int idx = bid * 2048 + q * 512 + t;   // 0..262143
            int which = idx >> 17;
            int r = idx & 131071;                  // k*1024 + d
            int k = r >> 10;
            int d = r & 1023;
            if (which == 0) wfet[r] = wfe[d * 128 + k];
            else            wpt[r]  = wp[d * 128 + k];
        }
        return;
    }

    __shared__ __align__(16) char W1s[128 * 256];  // bf16 [jo=128][k=128], swizzled
    __shared__ __align__(16) char W2s[32 * 256];   // bf16 [n=32][jo=128], swizzled
    __shared__ __align__(16) char efs[64 * 256];   // bf16 [j=64][k=128], swizzled; scratch at end
    __shared__ __align__(16) char hs [64 * 256];   // bf16 [j=64][jo=128], swizzled
    __shared__ float dist_row[512];
    __shared__ float xval[512];
    __shared__ unsigned char flgall[512];
    __shared__ float b1s[128];
    __shared__ float b2s[32];
    __shared__ float sred[16];
    __shared__ float dsump[128];

    const int row = blockIdx.x;     // b*512 + i
    const int b = row >> 9;
    const int i = row & 511;

    const int w  = t >> 6;          // wave 0..7
    const int l  = t & 63;          // lane
    const int lr = l & 15;          // frag row/col index
    const int lq = l >> 4;          // frag k-group

    // ---- stage W1 + W2 as bf16, swizzled ----
    for (int idx = t; idx < 2048 + 512; idx += 512) {
        const float* src; char* dst; int r16, c16;
        if (idx < 2048) { r16 = idx >> 4;          c16 = idx & 15; src = w1 + r16 * 128 + c16 * 8; dst = W1s; }
        else            { r16 = (idx - 2048) >> 4; c16 = (idx - 2048) & 15; src = w2 + r16 * 128 + c16 * 8; dst = W2s; }
        float4 f0 = *(const float4*)(src);
        float4 f1 = *(const float4*)(src + 4);
        uint4 pk;
        pk.x = (unsigned)f2bf(f0.x) | ((unsigned)f2bf(f0.y) << 16);
        pk.y = (unsigned)f2bf(f0.z) | ((unsigned)f2bf(f0.w) << 16);
        pk.z = (unsigned)f2bf(f1.x) | ((unsigned)f2bf(f1.y) << 16);
        pk.w = (unsigned)f2bf(f1.z) | ((unsigned)f2bf(f1.w) << 16);
        *(uint4*)(dst + swz(r16, c16 * 16)) = pk;
    }
    if (t < 128) b1s[t] = b1[t];
    if (t < 32)  b2s[t] = b2[t];

    const bool pad_i = padm[row] != 0;
    const bool force_adj = (clnm[row] != 0) || (molm[row] == 0);
    const float pix = pos[row * 3 + 0], piy = pos[row * 3 + 1], piz = pos[row * 3 + 2];

    // ---- per-j scalars for ALL 512 j, fully parallel (1 j / thread) ----
    {
        int2 e2 = ((const int2*)nte)[row * 512 + t];
        float mul = gmul[e2.x] + gmul[e2.y];
        float bia = gbias[e2.x] + gbias[e2.y];
        float dx = pix - pos[(b * 512 + t) * 3 + 0];
        float dy = piy - pos[(b * 512 + t) * 3 + 1];
        float dz = piz - pos[(b * 512 + t) * 3 + 2];
        float dist = sqrtf(dx * dx + dy * dy + dz * dz + 1e-12f);
        xval[t] = mul * dist + bia;
        int padj = padm[b * 512 + t] ? 1 : 0;
        int adje = (force_adj || adj[row * 512 + t]) ? 2 : 0;
        flgall[t] = (unsigned char)(padj | adje);
    }

    // ---- per-thread gaussian params: 8 consecutive k per thread ----
    const int k0 = (t & 15) * 8;
    const int js = t >> 4;          // j-slot 0..31
    float mean_q[8], istd_q[8], lnc_q[8], efacc[8];
    #pragma unroll
    for (int q = 0; q < 8; ++q) {
        float gsv = fabsf(gstd[k0 + q]) + 1e-5f;
        mean_q[q] = gmean[k0 + q];
        istd_q[q] = 1.0f / gsv;
        lnc_q[q]  = -logf(SQ2PI * gsv);
        efacc[q]  = 0.f;
    }

    __syncthreads();

    for (int tile = 0; tile < 8; ++tile) {
        const int j0 = tile * 64;
        // P1: ef-gen, k-major packed (+ previous tile's dist combine rides here)
        if (tile > 0 && t < 64) {
            int fl = flgall[j0 - 64 + t];
            bool masked = pad_i || (fl & 1) || !(fl & 2);
            dist_row[j0 - 64 + t] = masked ? MIN_F32 : (dsump[t] + dsump[64 + t]);
        }
        #pragma unroll
        for (int jj = 0; jj < 2; ++jj) {
            int j = js + jj * 32;
            float x  = xval[j0 + j];
            float mk = (flgall[j0 + j] & 1) ? 0.0f : 1.0f;
            unsigned pk[4];
            #pragma unroll
            for (int q = 0; q < 4; ++q) {
                float a0 = (x - mean_q[2*q+0]) * istd_q[2*q+0];
                float a1 = (x - mean_q[2*q+1]) * istd_q[2*q+1];
                float e0 = __expf(fmaf(a0 * a0, -0.5f, lnc_q[2*q+0]));
                float e1 = __expf(fmaf(a1 * a1, -0.5f, lnc_q[2*q+1]));
                efacc[2*q+0] = fmaf(e0, mk, efacc[2*q+0]);
                efacc[2*q+1] = fmaf(e1, mk, efacc[2*q+1]);
                pk[q] = pack_bf16x2(e0, e1);
            }
            *(uint4*)(efs + swz(j, 2 * k0)) = make_uint4(pk[0], pk[1], pk[2], pk[3]);
        }
        __syncthreads();
        // P2: GEMM1 swapped  D[jo][j] = W1 @ ef^T, gelu, packed b64 stores to hs[j][jo]
        {
            const int jobase = (w & 3) * 32;     // 2 jo-tiles
            const int jbase  = (w >> 2) * 32;    // 2 j-tiles
            f32x4 a00 = {0.f,0.f,0.f,0.f}, a01 = a00, a10 = a00, a11 = a00;
            #pragma unroll
            for (int ks = 0; ks < 4; ++ks) {
                int bcol = ks * 64 + lq * 16;
                short8 av0 = *(const short8*)(W1s + swz(jobase + lr, bcol));
                short8 av1 = *(const short8*)(W1s + swz(jobase + 16 + lr, bcol));
                short8 bv0 = *(const short8*)(efs + swz(jbase + lr, bcol));
                short8 bv1 = *(const short8*)(efs + swz(jbase + 16 + lr, bcol));
                a00 = __builtin_amdgcn_mfma_f32_16x16x32_bf16(av0, bv0, a00, 0, 0, 0);
                a01 = __builtin_amdgcn_mfma_f32_16x16x32_bf16(av0, bv1, a01, 0, 0, 0);
                a10 = __builtin_amdgcn_mfma_f32_16x16x32_bf16(av1, bv0, a10, 0, 0, 0);
                a11 = __builtin_amdgcn_mfma_f32_16x16x32_bf16(av1, bv1, a11, 0, 0, 0);
            }
            #pragma unroll
            for (int mi = 0; mi < 2; ++mi) {
                int jo0 = jobase + mi * 16 + lq * 4;
                float4 bb = *(const float4*)&b1s[jo0];
                #pragma unroll
                for (int ci = 0; ci < 2; ++ci) {
                    f32x4 acc = (mi == 0) ? (ci == 0 ? a00 : a01) : (ci == 0 ? a10 : a11);
                    int j = jbase + ci * 16 + lr;
                    float g0 = gelu_fast(acc[0] + bb.x);
                    float g1 = gelu_fast(acc[1] + bb.y);
                    float g2 = gelu_fast(acc[2] + bb.z);
                    float g3 = gelu_fast(acc[3] + bb.w);
                    uint2 pv = make_uint2(pack_bf16x2(g0, g1), pack_bf16x2(g2, g3));
                    *(uint2*)(hs + swz(j, 2 * jo0)) = pv;
                }
            }
        }
        __syncthreads();
        // P3: GEMM2 transposed  C'[n][j] = W2 @ h^T  (lockstep store slab)
        {
            const int mt = w >> 2;           // n-tile (0/1)
            const int jt2 = w & 3;           // j-tile
            f32x4 acc = (f32x4){0.f, 0.f, 0.f, 0.f};
            #pragma unroll
            for (int ks = 0; ks < 4; ++ks) {
                int bcol = ks * 64 + lq * 16;
                short8 av = *(const short8*)(W2s + swz(mt * 16 + lr, bcol));
                short8 bv = *(const short8*)(hs + swz(jt2 * 16 + lr, bcol));
                acc = __builtin_amdgcn_mfma_f32_16x16x32_bf16(av, bv, acc, 0, 0, 0);
            }
            int jl = jt2 * 16 + lr;
            int jg = j0 + jl;
            int fl = flgall[jg];
            bool kill = (fl & 1) || !(fl & 2);
            float dpart = 0.f;
            size_t base = ((size_t)(b * 32 + mt * 16 + lq * 4) * 512 + i) * 512 + jg;
            #pragma unroll
            for (int r = 0; r < 4; ++r) {
                float raw = acc[r] + b2s[mt * 16 + lq * 4 + r];
                dpart += raw;
                float outv = pad_i ? 0.0f : (kill ? NEG_BIG : raw);
                out_gab[base + (size_t)r * 262144] = outv;
            }
            dpart += __shfl_xor(dpart, 16);
            dpart += __shfl_xor(dpart, 32);
            if (l < 16) dsump[mt * 64 + jl] = dpart;
        }
        __syncthreads();
    }

    // last tile's dist combine + efsum flush (efs free -> scratch)
    float* rb = (float*)efs;
    if (t < 64) {
        int fl = flgall[448 + t];
        bool masked = pad_i || (fl & 1) || !(fl & 2);
        dist_row[448 + t] = masked ? MIN_F32 : (dsump[t] + dsump[64 + t]);
    }
    // rb[js*128 + k0 + q] = efacc[q]
    *(float4*)&rb[t * 8 + 0] = make_float4(efacc[0], efacc[1], efacc[2], efacc[3]);
    *(float4*)&rb[t * 8 + 4] = make_float4(efacc[4], efacc[5], efacc[6], efacc[7]);
    __syncthreads();
    if (t < 128) {
        float s = 0.f;
        #pragma unroll
        for (int sidx = 0; sidx < 32; ++sidx) s += rb[sidx * 128 + t];
        efsum[(size_t)row * 128 + t] = s;
    }

    // ---- softmax over dist_row ----
    float sv = dist_row[t] * SCALING_F;
    float v = sv;
    #pragma unroll
    for (int m = 32; m > 0; m >>= 1) v = fmaxf(v, __shfl_xor(v, m));
    if ((t & 63) == 0) sred[t >> 6] = v;
    __syncthreads();
    float mx = sred[0];
    #pragma unroll
    for (int w8 = 1; w8 < 8; ++w8) mx = fmaxf(mx, sred[w8]);
    float e = expf(sv - mx);
    v = e;
    #pragma unroll
    for (int m = 32; m > 0; m >>= 1) v += __shfl_xor(v, m);
    if ((t & 63) == 0) sred[8 + (t >> 6)] = v;
    __syncthreads();
    float sm = 0.f;
    #pragma unroll
    for (int w8 = 0; w8 < 8; ++w8) sm += sred[8 + w8];
    float p = e / sm;

    // ---- pfe1 via linearity: pfe1[k] = pw[k] . (sum_j p[j]*pos[j]) ----
    float px = pos[(b * 512 + t) * 3 + 0];
    float py = pos[(b * 512 + t) * 3 + 1];
    float pz = pos[(b * 512 + t) * 3 + 2];
    float vx = p * px, vy = p * py, vz = p * pz;
    #pragma unroll
    for (int m = 32; m > 0; m >>= 1) {
        vx += __shfl_xor(vx, m); vy += __shfl_xor(vy, m); vz += __shfl_xor(vz, m);
    }
    __syncthreads();      // rb re-use after efsum reads done
    if ((t & 63) == 0) {
        int w8 = t >> 6;
        rb[w8] = vx; rb[8 + w8] = vy; rb[16 + w8] = vz;
    }
    __syncthreads();
    if (t < 128) {
        float w0 = 0.f, w1v = 0.f, w2v = 0.f;
        #pragma unroll
        for (int w8 = 0; w8 < 8; ++w8) {
            w0 += rb[w8]; w1v += rb[8 + w8]; w2v += rb[16 + w8];
        }
        pfe1[(size_t)row * 128 + t] = pw[t * 3 + 0] * w0 + pw[t * 3 + 1] * w1v + pw[t * 3 + 2] * w2v;
    }
}

// ---------------- final projection: tiled f32 GEMM ----------------
__global__ __launch_bounds__(256) void pfe_kernel(
    const float* __restrict__ pfe1,
    const float* __restrict__ efsum,
    const float* __restrict__ wfet,   // [K=128][D=1024]
    const float* __restrict__ wpt,    // [K=128][D=1024]
    const float* __restrict__ pb,
    const unsigned char* __restrict__ padm,
    float* __restrict__ out)
{
    __shared__ __align__(16) float As[2 * 32 * 132];
    __shared__ __align__(16) float Bs[2 * 16 * 128];
    const int t  = threadIdx.x;
    const int tx = t & 31;
    const int ty = t >> 5;
    const int r0 = (blockIdx.x >> 3) * 32;
    const int d0 = (blockIdx.x & 7) * 128;

    #pragma unroll
    for (int q = 0; q < 16; ++q) {
        int ii = t + q * 256;
        int r = ii >> 7, k = ii & 127;
        As[(0 * 32 + r) * 132 + k] = pfe1 [(size_t)(r0 + r) * 128 + k];
        As[(1 * 32 + r) * 132 + k] = efsum[(size_t)(r0 + r) * 128 + k];
    }

    f32x4 acc[4];
    #pragma unroll
    for (int rr = 0; rr < 4; ++rr) acc[rr] = (f32x4){0.f, 0.f, 0.f, 0.f};

    for (int kc = 0; kc < 8; ++kc) {
        __syncthreads();
        #pragma unroll
        for (int q = 0; q < 2; ++q) {
            int ii = t + q * 256;
            int kr = ii >> 5, dq = ii & 31;
            f32x4 v0 = ((const f32x4*)(wfet + (size_t)(kc * 16 + kr) * 1024 + d0))[dq];
            f32x4 v1 = ((const f32x4*)(wpt  + (size_t)(kc * 16 + kr) * 1024 + d0))[dq];
            *(f32x4*)&Bs[(0 * 16 + kr) * 128 + dq * 4] = v0;
            *(f32x4*)&Bs[(1 * 16 + kr) * 128 + dq * 4] = v1;
        }
        __syncthreads();
        #pragma unroll
        for (int k4 = 0; k4 < 4; ++k4) {
            int kb = kc * 16 + k4 * 4;
            f32x4 a0[4], a1[4];
            #pragma unroll
            for (int rr = 0; rr < 4; ++rr) {
                int r = ty * 4 + rr;
                a0[rr] = *(const f32x4*)&As[(0 * 32 + r) * 132 + kb];
                a1[rr] = *(const f32x4*)&As[(1 * 32 + r) * 132 + kb];
            }
            #pragma unroll
            for (int kq = 0; kq < 4; ++kq) {
                f32x4 b0 = *(const f32x4*)&Bs[(0 * 16 + k4 * 4 + kq) * 128 + tx * 4];
                f32x4 b1 = *(const f32x4*)&Bs[(1 * 16 + k4 * 4 + kq) * 128 + tx * 4];
                #pragma unroll
                for (int rr = 0; rr < 4; ++rr) {
                    acc[rr] += a0[rr][kq] * b0 + a1[rr][kq] * b1;
                }
            }
        }
    }

    f32x4 bv = *(const f32x4*)&pb[d0 + tx * 4];
    #pragma unroll
    for (int rr = 0; rr < 4; ++rr) {
        int row = r0 + ty * 4 + rr;
        f32x4 o = acc[rr] + bv;
        if (padm[row]) o = (f32x4){0.f, 0.f, 0.f, 0.f};
        *(f32x4*)&out[(size_t)row * 1024 + d0 + tx * 4] = o;
    }
}

extern "C" void kernel_launch(void* const* d_in, const int* in_sizes, int n_in,
                              void* d_out, int out_size, void* d_ws, size_t ws_size,
                              hipStream_t stream) {
    const float* pos  = (const float*)d_in[0];
    const int*   nte  = (const int*)d_in[1];
    const unsigned char* adj  = (const unsigned char*)d_in[2];
    const unsigned char* padm = (const unsigned char*)d_in[3];
    const unsigned char* molm = (const unsigned char*)d_in[4];
    const unsigned char* clnm = (const unsigned char*)d_in[5];
    const float* pw    = (const float*)d_in[6];
    const float* wfe   = (const float*)d_in[7];
    const float* gmean = (const float*)d_in[8];
    const float* gstd  = (const float*)d_in[9];
    const float* gmul  = (const float*)d_in[10];
    const float* gbias = (const float*)d_in[11];
    const float* w1    = (const float*)d_in[12];
    const float* b1    = (const float*)d_in[13];
    const float* w2    = (const float*)d_in[14];
    const float* b2    = (const float*)d_in[15];
    const float* wp    = (const float*)d_in[16];
    const float* pb    = (const float*)d_in[17];

    float* out      = (float*)d_out;
    float* out_pfe  = out;
    float* out_gab  = out + (size_t)BB * LL * 1024;

    float* ws    = (float*)d_ws;
    float* pfe1  = ws;                  // 131072
    float* efsum = ws + 131072;         // 131072
    float* wfet  = ws + 262144;         // 131072
    float* wpt   = ws + 393216;         // 131072

    row_kernel<<<BB * LL + 128, 512, 0, stream>>>(pos, nte, adj, padm, molm, clnm,
                                                  gmean, gstd, gmul, gbias,
                                                  w1, b1, w2, b2, pw, wfe, wp,
                                                  out_gab, pfe1, efsum, wfet, wpt);
    pfe_kernel<<<256, 256, 0, stream>>>(pfe1, efsum, wfet, wpt, pb, padm, out_pfe);
}

// Round 14
// 103.559 us; speedup vs baseline: 1.7426x; 1.0579x over previous
//
#include <hip/hip_runtime.h>
#include <hip/hip_bf16.h>

typedef __attribute__((ext_vector_type(8))) short short8;
typedef __attribute__((ext_vector_type(4))) float f32x4;

static const int BB = 2;
static const int LL = 512;
#define MIN_F32 (-3.4028234663852886e+38f)
// Masked gab sentinel: must stay FINITE in bf16 (bf16(-FLT_MAX) -> -inf -> nan diff)
#define NEG_BIG (-1.0e38f)
#define SCALING_F 0.08838834764831845f
#define SQ2PI 2.5066282746310002f

// raw v_exp_f32: 2^x (R9-proven)
__device__ __forceinline__ float exp2_hw(float x) {
    float r; asm("v_exp_f32 %0, %1" : "=v"(r) : "v"(x)); return r;
}
// Fast exact-gelu: 0.5x(1+erf(x/sqrt2)) with A&S 7.1.26 erf (|err|<1.5e-7)
// Used only to BUILD the LUT (384 evals/block).
__device__ __forceinline__ float gelu_fast(float x) {
    float s  = x * 0.70710678118654752440f;
    float za = fabsf(s);
    float t  = __builtin_amdgcn_rcpf(fmaf(za, 0.3275911f, 1.0f));
    float p  = t * fmaf(t, fmaf(t, fmaf(t, fmaf(t, 1.061405429f, -1.453152027f),
                                        1.421413741f), -0.284496736f), 0.254829592f);
    float e  = __expf(-za * za);
    float q  = fmaf(-p, e, 1.0f);
    union { float f; unsigned u; } uq, us;
    uq.f = q; us.f = s;
    uq.u = (uq.u & 0x7FFFFFFFu) | (us.u & 0x80000000u);
    float hx = 0.5f * x;
    return fmaf(hx, uq.f, hx);
}
// packed bf16x2 via v_cvt_pk_bf16_f32 (RNE); lo -> low 16 bits
__device__ __forceinline__ unsigned pack_bf16x2(float lo, float hi) {
    __hip_bfloat162 h2 = __float22bfloat162_rn(float2{lo, hi});
    union { __hip_bfloat162 h; unsigned u; } v; v.h = h2;
    return v.u;
}
// f2bf scalar (weight staging only, once per block)
__device__ __forceinline__ unsigned short f2bf(float f) {
    union { float f; unsigned int u; } v; v.f = f;
    unsigned int u = v.u;
    return (unsigned short)((u + 0x7FFFu + ((u >> 16) & 1u)) >> 16);
}
// Row-swizzled LDS byte offset for [row][128 bf16] tiles (row stride 256B).
__device__ __forceinline__ int swz(int row, int bytecol) {
    return row * 256 + (bytecol ^ ((row & 7) << 4));
}

// ---------------- main fused row kernel: one block per (b,i), 8 waves ----------------
// R8 lockstep structure (best measured). Blocks >= 1024 do the wfe/wp transpose.
// R9-R11 lesson: wave-private barrier-free variants amplified gab HBM traffic 4-5x;
// lockstep per-tile store slabs keep L2 write merge clean.
// R14: gelu via 384-entry LDS LUT (linear interp, err ~1e-4 << bf16 quant) kills
// 2 transcendentals + ~4 VALU per eval x 128 evals/thread; ef-gen exp2-folded.
__global__ __launch_bounds__(512, 4) void row_kernel(
    const float* __restrict__ pos,
    const int*   __restrict__ nte,
    const unsigned char* __restrict__ adj,
    const unsigned char* __restrict__ padm,
    const unsigned char* __restrict__ molm,
    const unsigned char* __restrict__ clnm,
    const float* __restrict__ gmean,
    const float* __restrict__ gstd,
    const float* __restrict__ gmul,
    const float* __restrict__ gbias,
    const float* __restrict__ w1,
    const float* __restrict__ b1,
    const float* __restrict__ w2,
    const float* __restrict__ b2,
    const float* __restrict__ pw,
    const float* __restrict__ wfe,
    const float* __restrict__ wp,
    float* __restrict__ out_gab,
    float* __restrict__ pfe1,
    float* __restrict__ efsum,
    float* __restrict__ wfet,
    float* __restrict__ wpt)
{
    const int t = threadIdx.x;

    // ---- tail blocks: weight transpose for pfe_kernel ----
    if (blockIdx.x >= 1024) {
        int bid = blockIdx.x - 1024;          // 0..127
        #pragma unroll
        for (int q = 0; q < 4; ++q) {
            int idx = bid * 2048 + q * 512 + t;   // 0..262143
            int which = idx >> 17;
            int r = idx & 131071;                  // k*1024 + d
            int k = r >> 10;
            int d = r & 1023;
            if (which == 0) wfet[r] = wfe[d * 128 + k];
            else            wpt[r]  = wp[d * 128 + k];
        }
        return;
    }

    __shared__ __align__(16) char W1s[128 * 256];  // bf16 [jo=128][k=128], swizzled
    __shared__ __align__(16) char W2s[32 * 256];   // bf16 [n=32][jo=128], swizzled
    __shared__ __align__(16) char efs[64 * 256];   // bf16 [j=64][k=128], swizzled; scratch at end
    __shared__ __align__(16) char hs [64 * 256];   // bf16 [j=64][jo=128], swizzled
    __shared__ float dist_row[512];
    __shared__ float xval[512];
    __shared__ unsigned char flgall[512];
    __shared__ float b1s[128];
    __shared__ float b2s[32];
    __shared__ float sred[16];
    __shared__ float dsump[128];
    __shared__ float gelu_tab[384];   // gelu on [-6,6], step 1/32 (1536B; keeps 2 blk/CU)

    const int row = blockIdx.x;     // b*512 + i
    const int b = row >> 9;
    const int i = row & 511;

    const int w  = t >> 6;          // wave 0..7
    const int l  = t & 63;          // lane
    const int lr = l & 15;          // frag row/col index
    const int lq = l >> 4;          // frag k-group

    // ---- stage W1 + W2 as bf16, swizzled ----
    for (int idx = t; idx < 2048 + 512; idx += 512) {
        const float* src; char* dst; int r16, c16;
        if (idx < 2048) { r16 = idx >> 4;          c16 = idx & 15; src = w1 + r16 * 128 + c16 * 8; dst = W1s; }
        else            { r16 = (idx - 2048) >> 4; c16 = (idx - 2048) & 15; src = w2 + r16 * 128 + c16 * 8; dst = W2s; }
        float4 f0 = *(const float4*)(src);
        float4 f1 = *(const float4*)(src + 4);
        uint4 pk;
        pk.x = (unsigned)f2bf(f0.x) | ((unsigned)f2bf(f0.y) << 16);
        pk.y = (unsigned)f2bf(f0.z) | ((unsigned)f2bf(f0.w) << 16);
        pk.z = (unsigned)f2bf(f1.x) | ((unsigned)f2bf(f1.y) << 16);
        pk.w = (unsigned)f2bf(f1.z) | ((unsigned)f2bf(f1.w) << 16);
        *(uint4*)(dst + swz(r16, c16 * 16)) = pk;
    }
    if (t < 128) b1s[t] = b1[t];
    if (t < 32)  b2s[t] = b2[t];
    if (t < 384) gelu_tab[t] = gelu_fast((t - 192) * 0.03125f);

    const bool pad_i = padm[row] != 0;
    const bool force_adj = (clnm[row] != 0) || (molm[row] == 0);
    const float pix = pos[row * 3 + 0], piy = pos[row * 3 + 1], piz = pos[row * 3 + 2];

    // ---- per-j scalars for ALL 512 j, fully parallel (1 j / thread) ----
    {
        int2 e2 = ((const int2*)nte)[row * 512 + t];
        float mul = gmul[e2.x] + gmul[e2.y];
        float bia = gbias[e2.x] + gbias[e2.y];
        float dx = pix - pos[(b * 512 + t) * 3 + 0];
        float dy = piy - pos[(b * 512 + t) * 3 + 1];
        float dz = piz - pos[(b * 512 + t) * 3 + 2];
        float dist = sqrtf(dx * dx + dy * dy + dz * dz + 1e-12f);
        xval[t] = mul * dist + bia;
        int padj = padm[b * 512 + t] ? 1 : 0;
        int adje = (force_adj || adj[row * 512 + t]) ? 2 : 0;
        flgall[t] = (unsigned char)(padj | adje);
    }

    // ---- per-thread gaussian params: 8 consecutive k, exp2-folded (R9 numerics) ----
    const int k0 = (t & 15) * 8;
    const int js = t >> 4;          // j-slot 0..31
    float mean_q[8], istd_q[8], lnc_q[8], efacc[8];
    #pragma unroll
    for (int q = 0; q < 8; ++q) {
        float gsv = fabsf(gstd[k0 + q]) + 1e-5f;
        mean_q[q] = gmean[k0 + q];
        istd_q[q] = 0.84932180f / gsv;              // sqrt(0.5*log2(e))/sigma
        lnc_q[q]  = -log2f(SQ2PI * gsv);
        efacc[q]  = 0.f;
    }

    // gelu via LUT: xc=med3 -> f32 index -> ds_read2 interp; exact only needed to bf16.
    auto gelu_lut = [&](float x) -> float {
        float xc = fminf(fmaxf(x, -6.0f), 6.0f);
        float f  = fminf(fmaf(xc, 32.0f, 192.0f), 382.99f);
        float ff = floorf(f);
        float fr = f - ff;
        int idx = (int)ff;
        float v0 = gelu_tab[idx];
        float v1 = gelu_tab[idx + 1];
        float r = fmaf(fr, v1 - v0, v0);
        return x > 5.9f ? x : r;   // table[0]=gelu(-6)~-6e-9 covers the negative tail
    };

    __syncthreads();

    for (int tile = 0; tile < 8; ++tile) {
        const int j0 = tile * 64;
        // P1: ef-gen, k-major packed (+ previous tile's dist combine rides here)
        if (tile > 0 && t < 64) {
            int fl = flgall[j0 - 64 + t];
            bool masked = pad_i || (fl & 1) || !(fl & 2);
            dist_row[j0 - 64 + t] = masked ? MIN_F32 : (dsump[t] + dsump[64 + t]);
        }
        #pragma unroll
        for (int jj = 0; jj < 2; ++jj) {
            int j = js + jj * 32;
            float x  = xval[j0 + j];
            float mk = (flgall[j0 + j] & 1) ? 0.0f : 1.0f;
            unsigned pk[4];
            #pragma unroll
            for (int q = 0; q < 4; ++q) {
                float a0 = (x - mean_q[2*q+0]) * istd_q[2*q+0];
                float a1 = (x - mean_q[2*q+1]) * istd_q[2*q+1];
                float e0 = exp2_hw(fmaf(a0, -a0, lnc_q[2*q+0]));
                float e1 = exp2_hw(fmaf(a1, -a1, lnc_q[2*q+1]));
                efacc[2*q+0] = fmaf(e0, mk, efacc[2*q+0]);
                efacc[2*q+1] = fmaf(e1, mk, efacc[2*q+1]);
                pk[q] = pack_bf16x2(e0, e1);
            }
            *(uint4*)(efs + swz(j, 2 * k0)) = make_uint4(pk[0], pk[1], pk[2], pk[3]);
        }
        __syncthreads();
        // P2: GEMM1 swapped  D[jo][j] = W1 @ ef^T, gelu-LUT, packed b64 stores to hs[j][jo]
        {
            const int jobase = (w & 3) * 32;     // 2 jo-tiles
            const int jbase  = (w >> 2) * 32;    // 2 j-tiles
            f32x4 a00 = {0.f,0.f,0.f,0.f}, a01 = a00, a10 = a00, a11 = a00;
            #pragma unroll
            for (int ks = 0; ks < 4; ++ks) {
                int bcol = ks * 64 + lq * 16;
                short8 av0 = *(const short8*)(W1s + swz(jobase + lr, bcol));
                short8 av1 = *(const short8*)(W1s + swz(jobase + 16 + lr, bcol));
                short8 bv0 = *(const short8*)(efs + swz(jbase + lr, bcol));
                short8 bv1 = *(const short8*)(efs + swz(jbase + 16 + lr, bcol));
                a00 = __builtin_amdgcn_mfma_f32_16x16x32_bf16(av0, bv0, a00, 0, 0, 0);
                a01 = __builtin_amdgcn_mfma_f32_16x16x32_bf16(av0, bv1, a01, 0, 0, 0);
                a10 = __builtin_amdgcn_mfma_f32_16x16x32_bf16(av1, bv0, a10, 0, 0, 0);
                a11 = __builtin_amdgcn_mfma_f32_16x16x32_bf16(av1, bv1, a11, 0, 0, 0);
            }
            #pragma unroll
            for (int mi = 0; mi < 2; ++mi) {
                int jo0 = jobase + mi * 16 + lq * 4;
                float4 bb = *(const float4*)&b1s[jo0];
                #pragma unroll
                for (int ci = 0; ci < 2; ++ci) {
                    f32x4 acc = (mi == 0) ? (ci == 0 ? a00 : a01) : (ci == 0 ? a10 : a11);
                    int j = jbase + ci * 16 + lr;
                    float g0 = gelu_lut(acc[0] + bb.x);
                    float g1 = gelu_lut(acc[1] + bb.y);
                    float g2 = gelu_lut(acc[2] + bb.z);
                    float g3 = gelu_lut(acc[3] + bb.w);
                    uint2 pv = make_uint2(pack_bf16x2(g0, g1), pack_bf16x2(g2, g3));
                    *(uint2*)(hs + swz(j, 2 * jo0)) = pv;
                }
            }
        }
        __syncthreads();
        // P3: GEMM2 transposed  C'[n][j] = W2 @ h^T  (lockstep store slab)
        {
            const int mt = w >> 2;           // n-tile (0/1)
            const int jt2 = w & 3;           // j-tile
            f32x4 acc = (f32x4){0.f, 0.f, 0.f, 0.f};
            #pragma unroll
            for (int ks = 0; ks < 4; ++ks) {
                int bcol = ks * 64 + lq * 16;
                short8 av = *(const short8*)(W2s + swz(mt * 16 + lr, bcol));
                short8 bv = *(const short8*)(hs + swz(jt2 * 16 + lr, bcol));
                acc = __builtin_amdgcn_mfma_f32_16x16x32_bf16(av, bv, acc, 0, 0, 0);
            }
            int jl = jt2 * 16 + lr;
            int jg = j0 + jl;
            int fl = flgall[jg];
            bool kill = (fl & 1) || !(fl & 2);
            float dpart = 0.f;
            size_t base = ((size_t)(b * 32 + mt * 16 + lq * 4) * 512 + i) * 512 + jg;
            #pragma unroll
            for (int r = 0; r < 4; ++r) {
                float raw = acc[r] + b2s[mt * 16 + lq * 4 + r];
                dpart += raw;
                float outv = pad_i ? 0.0f : (kill ? NEG_BIG : raw);
                out_gab[base + (size_t)r * 262144] = outv;
            }
            dpart += __shfl_xor(dpart, 16);
            dpart += __shfl_xor(dpart, 32);
            if (l < 16) dsump[mt * 64 + jl] = dpart;
        }
        __syncthreads();
    }

    // last tile's dist combine + efsum flush (efs free -> scratch)
    float* rb = (float*)efs;
    if (t < 64) {
        int fl = flgall[448 + t];
        bool masked = pad_i || (fl & 1) || !(fl & 2);
        dist_row[448 + t] = masked ? MIN_F32 : (dsump[t] + dsump[64 + t]);
    }
    // rb[js*128 + k0 + q] = efacc[q]
    *(float4*)&rb[t * 8 + 0] = make_float4(efacc[0], efacc[1], efacc[2], efacc[3]);
    *(float4*)&rb[t * 8 + 4] = make_float4(efacc[4], efacc[5], efacc[6], efacc[7]);
    __syncthreads();
    if (t < 128) {
        float s = 0.f;
        #pragma unroll
        for (int sidx = 0; sidx < 32; ++sidx) s += rb[sidx * 128 + t];
        efsum[(size_t)row * 128 + t] = s;
    }

    // ---- softmax over dist_row ----
    float sv = dist_row[t] * SCALING_F;
    float v = sv;
    #pragma unroll
    for (int m = 32; m > 0; m >>= 1) v = fmaxf(v, __shfl_xor(v, m));
    if ((t & 63) == 0) sred[t >> 6] = v;
    __syncthreads();
    float mx = sred[0];
    #pragma unroll
    for (int w8 = 1; w8 < 8; ++w8) mx = fmaxf(mx, sred[w8]);
    float e = expf(sv - mx);
    v = e;
    #pragma unroll
    for (int m = 32; m > 0; m >>= 1) v += __shfl_xor(v, m);
    if ((t & 63) == 0) sred[8 + (t >> 6)] = v;
    __syncthreads();
    float sm = 0.f;
    #pragma unroll
    for (int w8 = 0; w8 < 8; ++w8) sm += sred[8 + w8];
    float p = e / sm;

    // ---- pfe1 via linearity: pfe1[k] = pw[k] . (sum_j p[j]*pos[j]) ----
    float px = pos[(b * 512 + t) * 3 + 0];
    float py = pos[(b * 512 + t) * 3 + 1];
    float pz = pos[(b * 512 + t) * 3 + 2];
    float vx = p * px, vy = p * py, vz = p * pz;
    #pragma unroll
    for (int m = 32; m > 0; m >>= 1) {
        vx += __shfl_xor(vx, m); vy += __shfl_xor(vy, m); vz += __shfl_xor(vz, m);
    }
    __syncthreads();      // rb re-use after efsum reads done
    if ((t & 63) == 0) {
        int w8 = t >> 6;
        rb[w8] = vx; rb[8 + w8] = vy; rb[16 + w8] = vz;
    }
    __syncthreads();
    if (t < 128) {
        float w0 = 0.f, w1v = 0.f, w2v = 0.f;
        #pragma unroll
        for (int w8 = 0; w8 < 8; ++w8) {
            w0 += rb[w8]; w1v += rb[8 + w8]; w2v += rb[16 + w8];
        }
        pfe1[(size_t)row * 128 + t] = pw[t * 3 + 0] * w0 + pw[t * 3 + 1] * w1v + pw[t * 3 + 2] * w2v;
    }
}

// ---------------- final projection: tiled f32 GEMM ----------------
__global__ __launch_bounds__(256) void pfe_kernel(
    const float* __restrict__ pfe1,
    const float* __restrict__ efsum,
    const float* __restrict__ wfet,   // [K=128][D=1024]
    const float* __restrict__ wpt,    // [K=128][D=1024]
    const float* __restrict__ pb,
    const unsigned char* __restrict__ padm,
    float* __restrict__ out)
{
    __shared__ __align__(16) float As[2 * 32 * 132];
    __shared__ __align__(16) float Bs[2 * 16 * 128];
    const int t  = threadIdx.x;
    const int tx = t & 31;
    const int ty = t >> 5;
    const int r0 = (blockIdx.x >> 3) * 32;
    const int d0 = (blockIdx.x & 7) * 128;

    #pragma unroll
    for (int q = 0; q < 16; ++q) {
        int ii = t + q * 256;
        int r = ii >> 7, k = ii & 127;
        As[(0 * 32 + r) * 132 + k] = pfe1 [(size_t)(r0 + r) * 128 + k];
        As[(1 * 32 + r) * 132 + k] = efsum[(size_t)(r0 + r) * 128 + k];
    }

    f32x4 acc[4];
    #pragma unroll
    for (int rr = 0; rr < 4; ++rr) acc[rr] = (f32x4){0.f, 0.f, 0.f, 0.f};

    for (int kc = 0; kc < 8; ++kc) {
        __syncthreads();
        #pragma unroll
        for (int q = 0; q < 2; ++q) {
            int ii = t + q * 256;
            int kr = ii >> 5, dq = ii & 31;
            f32x4 v0 = ((const f32x4*)(wfet + (size_t)(kc * 16 + kr) * 1024 + d0))[dq];
            f32x4 v1 = ((const f32x4*)(wpt  + (size_t)(kc * 16 + kr) * 1024 + d0))[dq];
            *(f32x4*)&Bs[(0 * 16 + kr) * 128 + dq * 4] = v0;
            *(f32x4*)&Bs[(1 * 16 + kr) * 128 + dq * 4] = v1;
        }
        __syncthreads();
        #pragma unroll
        for (int k4 = 0; k4 < 4; ++k4) {
            int kb = kc * 16 + k4 * 4;
            f32x4 a0[4], a1[4];
            #pragma unroll
            for (int rr = 0; rr < 4; ++rr) {
                int r = ty * 4 + rr;
                a0[rr] = *(const f32x4*)&As[(0 * 32 + r) * 132 + kb];
                a1[rr] = *(const f32x4*)&As[(1 * 32 + r) * 132 + kb];
            }
            #pragma unroll
            for (int kq = 0; kq < 4; ++kq) {
                f32x4 b0 = *(const f32x4*)&Bs[(0 * 16 + k4 * 4 + kq) * 128 + tx * 4];
                f32x4 b1 = *(const f32x4*)&Bs[(1 * 16 + k4 * 4 + kq) * 128 + tx * 4];
                #pragma unroll
                for (int rr = 0; rr < 4; ++rr) {
                    acc[rr] += a0[rr][kq] * b0 + a1[rr][kq] * b1;
                }
            }
        }
    }

    f32x4 bv = *(const f32x4*)&pb[d0 + tx * 4];
    #pragma unroll
    for (int rr = 0; rr < 4; ++rr) {
        int row = r0 + ty * 4 + rr;
        f32x4 o = acc[rr] + bv;
        if (padm[row]) o = (f32x4){0.f, 0.f, 0.f, 0.f};
        *(f32x4*)&out[(size_t)row * 1024 + d0 + tx * 4] = o;
    }
}

extern "C" void kernel_launch(void* const* d_in, const int* in_sizes, int n_in,
                              void* d_out, int out_size, void* d_ws, size_t ws_size,
                              hipStream_t stream) {
    const float* pos  = (const float*)d_in[0];
    const int*   nte  = (const int*)d_in[1];
    const unsigned char* adj  = (const unsigned char*)d_in[2];
    const unsigned char* padm = (const unsigned char*)d_in[3];
    const unsigned char* molm = (const unsigned char*)d_in[4];
    const unsigned char* clnm = (const unsigned char*)d_in[5];
    const float* pw    = (const float*)d_in[6];
    const float* wfe   = (const float*)d_in[7];
    const float* gmean = (const float*)d_in[8];
    const float* gstd  = (const float*)d_in[9];
    const float* gmul  = (const float*)d_in[10];
    const float* gbias = (const float*)d_in[11];
    const float* w1    = (const float*)d_in[12];
    const float* b1    = (const float*)d_in[13];
    const float* w2    = (const float*)d_in[14];
    const float* b2    = (const float*)d_in[15];
    const float* wp    = (const float*)d_in[16];
    const float* pb    = (const float*)d_in[17];

    float* out      = (float*)d_out;
    float* out_pfe  = out;
    float* out_gab  = out + (size_t)BB * LL * 1024;

    float* ws    = (float*)d_ws;
    float* pfe1  = ws;                  // 131072
    float* efsum = ws + 131072;         // 131072
    float* wfet  = ws + 262144;         // 131072
    float* wpt   = ws + 393216;         // 131072

    row_kernel<<<BB * LL + 128, 512, 0, stream>>>(pos, nte, adj, padm, molm, clnm,
                                                  gmean, gstd, gmul, gbias,
                                                  w1, b1, w2, b2, pw, wfe, wp,
                                                  out_gab, pfe1, efsum, wfet, wpt);
    pfe_kernel<<<256, 256, 0, stream>>>(pfe1, efsum, wfet, wpt, pb, padm, out_pfe);
}